// Round 17
// baseline (382.604 us; speedup 1.0000x reference)
//
#include <hip/hip_runtime.h>
#include <stdint.h>

#define TOKENS 8192
#define OUT_F  4096
#define IN_F   4096
#define RNK    8
#define KPRUNE 8388608u
#define CAP3   16384u

typedef unsigned short u16;
typedef float  f32x4  __attribute__((ext_vector_type(4)));
typedef short  bf16x8 __attribute__((ext_vector_type(8)));
typedef unsigned short u16x4 __attribute__((ext_vector_type(4)));
typedef unsigned short u16x8 __attribute__((ext_vector_type(8)));

// ---- workspace layout (bytes) ----
#define XB_OFF    0ull                 // xB  : 8192*4096 bf16 = 64 MiB
#define WB_OFF    67108864ull          // wB  : 4096*4096 bf16 = 32 MiB
#define CTL_OFF   100663296ull
//   ctl: h1[4096] h2[4096] cnt3[1] list3[CAP3]
#define H1_OFF    0
#define H2_OFF    16384
#define CNT3_OFF  32768
#define LIST3_OFF 32772
#define CTL_ZERO_U32 8193              // h1+h2+cnt3

__device__ __forceinline__ u16 f2bf(float f) {
    uint32_t u = __float_as_uint(f);
    u += 0x7fffu + ((u >> 16) & 1u);   // RNE
    return (u16)(u >> 16);
}

__device__ __forceinline__ uint32_t fkey(float s) {
    uint32_t u = __float_as_uint(s);
    return (u & 0x80000000u) ? ~u : (u | 0x80000000u);
}

// ---- inline k-th select over a 4096-bin global histogram (256 threads) ----
__device__ __forceinline__ void hsel(const uint32_t* __restrict__ hist, uint32_t k,
                                     volatile uint32_t* scr,
                                     uint32_t& bin, uint32_t& below)
{
    const int t = threadIdx.x;
    const int lane = t & 63, w = t >> 6;
    uint32_t v[16]; uint32_t s = 0;
#pragma unroll
    for (int j = 0; j < 16; ++j) { v[j] = hist[t*16 + j]; s += v[j]; }
    uint32_t sc = s;                       // inclusive wave scan
#pragma unroll
    for (int d = 1; d < 64; d <<= 1) {
        uint32_t o = __shfl_up(sc, d, 64);
        if (lane >= d) sc += o;
    }
    if (lane == 63) scr[w] = sc;           // wave totals
    __syncthreads();
    uint32_t woff = 0;
    for (int ww = 0; ww < w; ++ww) woff += scr[ww];
    const uint32_t pre = woff + sc - s;    // exclusive prefix of thread t
    if (pre < k && pre + s >= k) {         // unique winner
        uint32_t bb = pre;
#pragma unroll
        for (int j = 0; j < 16; ++j) {
            if (bb < k && bb + v[j] >= k) { scr[4] = (uint32_t)(t*16 + j); scr[5] = bb; }
            bb += v[j];
        }
    }
    __syncthreads();
    bin = scr[4]; below = scr[5];
    __syncthreads();
}

// ---- shared score recompute: 2 rows x 4 cols, IDENTICAL FMA sequence in all
// three passes (dependence-chained fmaf => bit-identical, deterministic).
struct S2 { float4 w0, w1; uint4 k0, k1; };
__device__ __forceinline__ S2 score2(const float* __restrict__ W,
                                     const float* __restrict__ V,
                                     const float* __restrict__ B,
                                     const float* __restrict__ C,
                                     const float* uu0, const float* uu1,
                                     const float* aa0, const float* aa1,
                                     float ro0, float ro1, int o0, int i)
{
    const float4 cc = *(const float4*)&C[i];
    float4 w0 = *(const float4*)&W[(size_t)o0*IN_F + i];
    float4 w1 = *(const float4*)&W[(size_t)(o0+1)*IN_F + i];
#pragma unroll
    for (int r = 0; r < RNK; ++r) {
        const float4 v4 = *(const float4*)&V[r*IN_F + i];
        const float a0 = uu0[r], a1 = uu1[r];
        w0.x = fmaf(a0, v4.x, w0.x); w0.y = fmaf(a0, v4.y, w0.y);
        w0.z = fmaf(a0, v4.z, w0.z); w0.w = fmaf(a0, v4.w, w0.w);
        w1.x = fmaf(a1, v4.x, w1.x); w1.y = fmaf(a1, v4.y, w1.y);
        w1.z = fmaf(a1, v4.z, w1.z); w1.w = fmaf(a1, v4.w, w1.w);
    }
    float4 s0, s1;
    s0.x = fabsf(w0.x); s0.y = fabsf(w0.y); s0.z = fabsf(w0.z); s0.w = fabsf(w0.w);
    s1.x = fabsf(w1.x); s1.y = fabsf(w1.y); s1.z = fabsf(w1.z); s1.w = fabsf(w1.w);
#pragma unroll
    for (int r = 0; r < RNK; ++r) {
        const float4 b4 = *(const float4*)&B[r*IN_F + i];
        const float a0 = aa0[r], a1 = aa1[r];
        s0.x = fmaf(a0, b4.x, s0.x); s0.y = fmaf(a0, b4.y, s0.y);
        s0.z = fmaf(a0, b4.z, s0.z); s0.w = fmaf(a0, b4.w, s0.w);
        s1.x = fmaf(a1, b4.x, s1.x); s1.y = fmaf(a1, b4.y, s1.y);
        s1.z = fmaf(a1, b4.z, s1.z); s1.w = fmaf(a1, b4.w, s1.w);
    }
    s0.x += ro0 + cc.x; s0.y += ro0 + cc.y; s0.z += ro0 + cc.z; s0.w += ro0 + cc.w;
    s1.x += ro1 + cc.x; s1.y += ro1 + cc.y; s1.z += ro1 + cc.z; s1.w += ro1 + cc.w;
    S2 o;
    o.w0 = w0; o.w1 = w1;
    o.k0.x = fkey(s0.x); o.k0.y = fkey(s0.y); o.k0.z = fkey(s0.z); o.k0.w = fkey(s0.w);
    o.k1.x = fkey(s1.x); o.k1.y = fkey(s1.y); o.k1.z = fkey(s1.z); o.k1.w = fkey(s1.w);
    return o;
}

#define LOAD_ROWPARAMS                                                        \
    float uu0[RNK], uu1[RNK], aa0[RNK], aa1[RNK];                             \
    _Pragma("unroll") for (int r = 0; r < RNK; ++r) {                         \
        uu0[r] = U[o0*RNK + r];   uu1[r] = U[(o0+1)*RNK + r];                 \
        aa0[r] = A[o0*RNK + r];   aa1[r] = A[(o0+1)*RNK + r];                 \
    }                                                                         \
    const float ro0 = R[o0], ro1 = R[o0 + 1];

// ---------------- x -> bf16 (+ ctl zeroing folded in) ----------------
__global__ void convx_kernel(const float* __restrict__ x, u16* __restrict__ xB,
                             uint32_t* __restrict__ ctl)
{
    const int t = threadIdx.x;
    if (blockIdx.x < 33) {
        const int i = blockIdx.x * 256 + t;
        if (i < CTL_ZERO_U32) ctl[i] = 0u;
    }
    const size_t idx = (size_t)blockIdx.x * 256 + t;
    const float4* xv = (const float4*)x;
    float4 a = xv[idx*2];
    float4 b = xv[idx*2 + 1];
    u16x8 o;
    o[0]=f2bf(a.x); o[1]=f2bf(a.y); o[2]=f2bf(a.z); o[3]=f2bf(a.w);
    o[4]=f2bf(b.x); o[5]=f2bf(b.y); o[6]=f2bf(b.z); o[7]=f2bf(b.w);
    *((u16x8*)xB + idx) = o;
}

// ---------------- pass 1: 12-bit histogram only (no stores) ----------------
__global__ void prep_kernel(const float* __restrict__ W, const float* __restrict__ U,
                            const float* __restrict__ V, const float* __restrict__ A,
                            const float* __restrict__ B, const float* __restrict__ R,
                            const float* __restrict__ C, uint32_t* __restrict__ hist1)
{
    __shared__ uint32_t lh[4096];
    const int o0 = blockIdx.x * 2, t = threadIdx.x;
    for (int b = t; b < 4096; b += 256) lh[b] = 0u;
    LOAD_ROWPARAMS
    __syncthreads();
    for (int j = 0; j < IN_F/1024; ++j) {
        const int i = j*1024 + t*4;
        S2 s = score2(W, V, B, C, uu0, uu1, aa0, aa1, ro0, ro1, o0, i);
        atomicAdd(&lh[s.k0.x >> 20], 1u); atomicAdd(&lh[s.k0.y >> 20], 1u);
        atomicAdd(&lh[s.k0.z >> 20], 1u); atomicAdd(&lh[s.k0.w >> 20], 1u);
        atomicAdd(&lh[s.k1.x >> 20], 1u); atomicAdd(&lh[s.k1.y >> 20], 1u);
        atomicAdd(&lh[s.k1.z >> 20], 1u); atomicAdd(&lh[s.k1.w >> 20], 1u);
    }
    __syncthreads();
    for (int b = t; b < 4096; b += 256) { uint32_t c = lh[b]; if (c) atomicAdd(&hist1[b], c); }
}

// ---------------- pass 2: inline select1 + mid-12 histogram within b1 ----------------
__global__ void hist2r_kernel(const float* __restrict__ W, const float* __restrict__ U,
                              const float* __restrict__ V, const float* __restrict__ A,
                              const float* __restrict__ B, const float* __restrict__ R,
                              const float* __restrict__ C, const uint32_t* __restrict__ hist1,
                              uint32_t* __restrict__ hist2)
{
    __shared__ uint32_t lh[4096];
    __shared__ uint32_t scr[6];
    const int o0 = blockIdx.x * 2, t = threadIdx.x;
    uint32_t b1, below1;
    hsel(hist1, KPRUNE, scr, b1, below1);
    for (int b = t; b < 4096; b += 256) lh[b] = 0u;
    LOAD_ROWPARAMS
    __syncthreads();
    for (int j = 0; j < IN_F/1024; ++j) {
        const int i = j*1024 + t*4;
        S2 s = score2(W, V, B, C, uu0, uu1, aa0, aa1, ro0, ro1, o0, i);
        if ((s.k0.x >> 20) == b1) atomicAdd(&lh[(s.k0.x >> 8) & 0xFFFu], 1u);
        if ((s.k0.y >> 20) == b1) atomicAdd(&lh[(s.k0.y >> 8) & 0xFFFu], 1u);
        if ((s.k0.z >> 20) == b1) atomicAdd(&lh[(s.k0.z >> 8) & 0xFFFu], 1u);
        if ((s.k0.w >> 20) == b1) atomicAdd(&lh[(s.k0.w >> 8) & 0xFFFu], 1u);
        if ((s.k1.x >> 20) == b1) atomicAdd(&lh[(s.k1.x >> 8) & 0xFFFu], 1u);
        if ((s.k1.y >> 20) == b1) atomicAdd(&lh[(s.k1.y >> 8) & 0xFFFu], 1u);
        if ((s.k1.z >> 20) == b1) atomicAdd(&lh[(s.k1.z >> 8) & 0xFFFu], 1u);
        if ((s.k1.w >> 20) == b1) atomicAdd(&lh[(s.k1.w >> 8) & 0xFFFu], 1u);
    }
    __syncthreads();
    for (int b = t; b < 4096; b += 256) { uint32_t c = lh[b]; if (c) atomicAdd(&hist2[b], c); }
}

// ---------------- pass 3: inline selects, write FINAL masked wB, collect ties ----------------
__global__ void applyr_kernel(const float* __restrict__ W, const float* __restrict__ U,
                              const float* __restrict__ V, const float* __restrict__ A,
                              const float* __restrict__ B, const float* __restrict__ R,
                              const float* __restrict__ C, const uint32_t* __restrict__ hist1,
                              const uint32_t* __restrict__ hist2, u16* __restrict__ wB,
                              uint32_t* __restrict__ cnt3, uint32_t* __restrict__ list3)
{
    __shared__ uint32_t scr[6];
    const int o0 = blockIdx.x * 2, t = threadIdx.x;
    uint32_t b1, below1, b2, below2;
    hsel(hist1, KPRUNE, scr, b1, below1);
    hsel(hist2, KPRUNE - below1, scr, b2, below2);
    const uint32_t pfx = (b1 << 12) | b2;
    LOAD_ROWPARAMS
    for (int j = 0; j < IN_F/1024; ++j) {
        const int i = j*1024 + t*4;
        S2 s = score2(W, V, B, C, uu0, uu1, aa0, aa1, ro0, ro1, o0, i);
        const float w0a[4] = {s.w0.x, s.w0.y, s.w0.z, s.w0.w};
        const float w1a[4] = {s.w1.x, s.w1.y, s.w1.z, s.w1.w};
        const uint32_t k0a[4] = {s.k0.x, s.k0.y, s.k0.z, s.k0.w};
        const uint32_t k1a[4] = {s.k1.x, s.k1.y, s.k1.z, s.k1.w};
        u16x4 b0, b1v;
#pragma unroll
        for (int e = 0; e < 4; ++e) {
            const uint32_t hi = k0a[e] >> 8;
            b0[e] = (hi < pfx) ? (u16)0 : f2bf(w0a[e]);
            if (hi == pfx) {
                uint32_t sl = atomicAdd(cnt3, 1u);
                if (sl < CAP3) list3[sl] = ((uint32_t)(o0*IN_F + i + e) << 8) | (k0a[e] & 0xFFu);
            }
        }
#pragma unroll
        for (int e = 0; e < 4; ++e) {
            const uint32_t hi = k1a[e] >> 8;
            b1v[e] = (hi < pfx) ? (u16)0 : f2bf(w1a[e]);
            if (hi == pfx) {
                uint32_t sl = atomicAdd(cnt3, 1u);
                if (sl < CAP3) list3[sl] = ((uint32_t)((o0+1)*IN_F + i + e) << 8) | (k1a[e] & 0xFFu);
            }
        }
        *(u16x4*)&wB[(size_t)o0*IN_F + i]     = b0;
        *(u16x4*)&wB[(size_t)(o0+1)*IN_F + i] = b1v;
    }
}

// ---------------- selfix: inline selects + exact stable pruning within prefix ----------------
__global__ void selfix_kernel(const uint32_t* __restrict__ hist1, const uint32_t* __restrict__ hist2,
                              const uint32_t* __restrict__ cnt3, const uint32_t* __restrict__ list3,
                              u16* __restrict__ wB)
{
    __shared__ uint32_t lst[CAP3];
    __shared__ uint32_t lhist[256];
    __shared__ uint32_t sv[2];
    __shared__ uint32_t scr[6];
    const int t = threadIdx.x;
    uint32_t b1, below1, b2, below2;
    hsel(hist1, KPRUNE, scr, b1, below1);
    hsel(hist2, KPRUNE - below1, scr, b2, below2);
    const uint32_t k3 = KPRUNE - below1 - below2;   // >= 1
    uint32_t n = *cnt3; if (n > CAP3) n = CAP3;
    lhist[t] = 0u;
    __syncthreads();
    for (uint32_t i = t; i < n; i += 256) {
        const uint32_t e = list3[i];
        lst[i] = e;
        atomicAdd(&lhist[e & 0xFFu], 1u);
    }
    __syncthreads();
    uint32_t pre = 0;
    for (int b = 0; b < t; ++b) pre += lhist[b];
    if (pre < k3 && pre + lhist[t] >= k3) {
        sv[0] = (uint32_t)t;
        sv[1] = k3 - pre;                    // ties at b3 to prune (>=1)
    }
    __syncthreads();
    const uint32_t b3 = sv[0], p = sv[1];
    for (uint32_t i = t; i < n; i += 256) {
        const uint32_t e = lst[i];
        const uint32_t lo = e & 0xFFu;
        if (lo < b3) { wB[e >> 8] = 0u; continue; }
        if (lo != b3) continue;
        uint32_t rank = 0;
        for (uint32_t j = 0; j < n; ++j) {
            const uint32_t f = lst[j];
            rank += ((f & 0xFFu) == b3 && f < e) ? 1u : 0u;   // same low8 -> flat-idx order
        }
        if (rank < p) wB[e >> 8] = 0u;
    }
}

// == 256x256 MERGED-4-phase bf16 NT GEMM, full register pipeline ==
// 4 merged phases per tile-pair (32 MFMA each), 4 barriers + 4 lgkmcnt(0) total
// (was 10/8). Staging: mp1={a0h1n,a1h1n} mp2={B0S x2} mp3={A0H0} mp4={B1S x2,A1H0}.
// Invariant: a slot staged at mp_k had its last preload-read drained by an earlier
// lgkmcnt(0) with an intervening barrier (audited per-slot). vmcnt: issues 4/4/2/6
// per mp -> vmcnt(8)@mp2 drains the odd tile, vmcnt(6)@mp4 drains the even tile;
// mid-barrier upgrades to cross-wave before the next-tile register preloads.
#define A0H0   0
#define A0H1_0 16384
#define A0H1_1 32768
#define B0S    49152
#define A1H0   81920
#define A1H1_0 98304
#define A1H1_1 114688
#define B1S    131072

__device__ __forceinline__ void gl_lds16(const char* src, char* dst) {
    __builtin_amdgcn_global_load_lds((const __attribute__((address_space(1))) void*)src,
                                     (__attribute__((address_space(3))) void*)dst, 16, 0, 0);
}

__global__ __launch_bounds__(512, 2) void gemm256_kernel(const u16* __restrict__ xB,
                                                         const u16* __restrict__ wB,
                                                         const float* __restrict__ bias,
                                                         float* __restrict__ out)
{
    __shared__ char ldsc[163840];
    const int t    = threadIdx.x;
    const int lane = t & 63;
    const int wid  = t >> 6;
    const int wm   = wid >> 2;     // 0..1
    const int wn   = wid & 3;      // 0..3
    const int bid  = blockIdx.x;
    const int bn   = bid & 15;     // N/256 = 16
    const int bm   = bid >> 4;     // M/256 = 32

    const int l15 = lane & 15;
    const int kb  = (lane >> 4) << 4;
    const int rowA = 16*wm + l15;
    const int rowB = (wn & 1)*64 + l15;
    const int baseA = rowA*64 + (kb ^ (((rowA >> 1) & 3) << 4));
    const int baseB = rowB*64 + (kb ^ (((rowB >> 1) & 3) << 4));
    const char* aB0 = ldsc + baseA;
    const char* aB1 = ldsc + A1H0 + baseA;
    const char* bB0 = ldsc + B0S + (wn >> 1)*16384 + baseB;
    const char* bB1 = bB0 + (B1S - B0S);

    const int scol = ((t & 3) * 16) ^ (((t >> 3) & 3) << 4);
    const char* pA = (const char*)xB + ((size_t)(bm*256 + (t >> 2))) * (IN_F*2) + scol;
    const char* pB = (const char*)wB + ((size_t)(bn*256 + (t >> 2))) * (IN_F*2) + scol;
    const int tb16 = t * 16;

#define STAGEH(pG, slot, h, tile) do {                                        \
    const char* _s = (pG) + (size_t)(tile)*128 + (size_t)(h)*(128*IN_F*2);    \
    char* _d = ldsc + (slot) + tb16;                                          \
    gl_lds16(_s, _d);                                                         \
    gl_lds16(_s + 64, _d + 8192);                                             \
} while (0)

    f32x4  acc[8][4] = {};
    bf16x8 be[4][2], bo[4][2];     // B register double-buffer (even/odd tiles)
    bf16x8 au[2][2], av[2][2];     // A quadrant double-buffer

#define LOADBD(dst, bp) do {                                                  \
    _Pragma("unroll") for (int ni = 0; ni < 4; ++ni)                          \
    _Pragma("unroll") for (int kk = 0; kk < 2; ++kk)                          \
        dst[ni][kk] = *(const bf16x8*)((bp) + ni*1024 + kk*8192);             \
} while (0)

#define LOADAD(dst, ap, slot, q, mo) do {                                     \
    _Pragma("unroll") for (int mm = 0; mm < 2; ++mm)                          \
    _Pragma("unroll") for (int kk = 0; kk < 2; ++kk)                          \
        dst[mm][kk] = *(const bf16x8*)((ap) + (slot) +                        \
                      (2*(q)+mm-(mo))*2048 + kk*8192);                        \
} while (0)

#define MFMAQ(q, bb, aa) do {                                                 \
    _Pragma("unroll") for (int mm = 0; mm < 2; ++mm)                          \
    _Pragma("unroll") for (int ni = 0; ni < 4; ++ni)                          \
    _Pragma("unroll") for (int kk = 0; kk < 2; ++kk)                          \
        acc[2*(q)+mm][ni] = __builtin_amdgcn_mfma_f32_16x16x32_bf16(          \
            aa[mm][kk], bb[ni][kk], acc[2*(q)+mm][ni], 0, 0, 0);              \
} while (0)

#define LGK0 asm volatile("s_waitcnt lgkmcnt(0)" ::: "memory");
#define BAR  __builtin_amdgcn_s_barrier();
#define PRIO1 __builtin_amdgcn_s_setprio(1);
#define PRIO0 __builtin_amdgcn_s_setprio(0);

#define STQ(q) do {                                                           \
    _Pragma("unroll") for (int mm = 0; mm < 2; ++mm) {                        \
        const int r0 = orow0 + 32*(2*(q)+mm);                                 \
        _Pragma("unroll") for (int ni = 0; ni < 4; ++ni) {                    \
            f32x4 v = acc[2*(q)+mm][ni];                                      \
            const int col = ocol0 + ni*16;                                    \
            _Pragma("unroll") for (int e = 0; e < 4; ++e)                     \
                out[(size_t)(r0 + e)*OUT_F + col] = v[e] + bv[ni];            \
        }                                                                     \
    }                                                                         \
} while (0)

    // ---- prologue: stage tiles 0 and 1, then preload tile0 B + A(q0,q1)
    STAGEH(pA, A0H1_0, 1, 0);
    STAGEH(pB, B0S,         0, 0);
    STAGEH(pB, B0S + 16384, 1, 0);
    STAGEH(pA, A0H0, 0, 0);
    STAGEH(pA, A1H1_0, 1, 1);
    STAGEH(pB, B1S,         0, 1);
    STAGEH(pB, B1S + 16384, 1, 1);
    STAGEH(pA, A1H0, 0, 1);
    asm volatile("s_waitcnt vmcnt(8)" ::: "memory");   // tile0's 4 half-tiles landed
    BAR
    LOADBD(be, bB0);
    LOADAD(au, aB0, A0H0, 0, 0);
    LOADAD(av, aB0, A0H0, 1, 0);

#pragma unroll 1
    for (int j = 0; j < 31; ++j) {          // tiles 0..61; 62,63 peeled
        const int se = 2*j + 2;
        const int so = 2*j + 3;
        const int pc = j & 1;
        const int a0h1c = pc ? A0H1_1 : A0H1_0;
        const int a0h1n = pc ? A0H1_0 : A0H1_1;
        const int a1h1c = pc ? A1H1_1 : A1H1_0;
        const int a1h1n = pc ? A1H1_0 : A1H1_1;

        // ---- mp1: even q0,q1 ----
        STAGEH(pA, a0h1n, 1, se);
        STAGEH(pA, a1h1n, 1, so);
        LGK0 PRIO1
        MFMAQ(0, be, au);
        LOADAD(au, aB0, a0h1c, 2, 4);
        MFMAQ(1, be, av);
        LOADAD(av, aB0, a0h1c, 3, 4);
        PRIO0 BAR

        // ---- mp2: even q2,q3 ; vmcnt(8)+BAR -> odd tile resident; preload it ----
        STAGEH(pB, B0S,         0, se);
        STAGEH(pB, B0S + 16384, 1, se);
        LGK0 PRIO1
        MFMAQ(2, be, au);
        MFMAQ(3, be, av);
        PRIO0
        asm volatile("s_waitcnt vmcnt(8)" ::: "memory");
        BAR
        LOADBD(bo, bB1);
        LOADAD(au, aB1, 0, 0, 0);
        LOADAD(av, aB1, 0, 1, 0);

        // ---- mp3: odd q0,q1 ----
        STAGEH(pA, A0H0, 0, se);
        LGK0 PRIO1
        MFMAQ(0, bo, au);
        LOADAD(au, aB1, a1h1c - A1H0, 2, 4);
        MFMAQ(1, bo, av);
        LOADAD(av, aB1, a1h1c - A1H0, 3, 4);
        PRIO0 BAR

        // ---- mp4: odd q2,q3 ; vmcnt(6)+BAR -> even tile resident; preload it ----
        STAGEH(pB, B1S,         0, so);
        STAGEH(pB, B1S + 16384, 1, so);
        STAGEH(pA, A1H0, 0, so);
        LGK0 PRIO1
        MFMAQ(2, bo, au);
        MFMAQ(3, bo, av);
        PRIO0
        asm volatile("s_waitcnt vmcnt(6)" ::: "memory");
        BAR
        LOADBD(be, bB0);
        LOADAD(au, aB0, A0H0, 0, 0);
        LOADAD(av, aB0, A0H0, 1, 0);
    }

    // ---- peeled tiles 62 + 63: no staging; stores fused into tile 63
    const int orow0 = bm*256 + 16*wm + ((lane >> 4) << 2);
    const int ocol0 = bn*256 + 64*wn + l15;
    float bv[4];
#pragma unroll
    for (int ni = 0; ni < 4; ++ni) bv[ni] = bias[ocol0 + ni*16];

    // tile 62 (even; be/au/av preloaded at j=30 mp4); parity j=31 -> *_1 slots
    LGK0 PRIO1
    MFMAQ(0, be, au);
    LOADAD(au, aB0, A0H1_1, 2, 4);
    MFMAQ(1, be, av);
    LOADAD(av, aB0, A0H1_1, 3, 4);
    PRIO0
    LGK0 PRIO1
    MFMAQ(2, be, au);
    MFMAQ(3, be, av);
    PRIO0
    asm volatile("s_waitcnt vmcnt(0)" ::: "memory");   // tile 63 landed
    BAR
    LOADBD(bo, bB1);
    LOADAD(au, aB1, 0, 0, 0);
    LOADAD(av, aB1, 0, 1, 0);

    // tile 63 (odd), stores fused per merged phase
    LGK0 PRIO1
    MFMAQ(0, bo, au);
    LOADAD(au, aB1, A1H1_1 - A1H0, 2, 4);
    MFMAQ(1, bo, av);
    LOADAD(av, aB1, A1H1_1 - A1H0, 3, 4);
    PRIO0
    STQ(0); STQ(1);
    LGK0 PRIO1
    MFMAQ(2, bo, au);
    MFMAQ(3, bo, av);
    PRIO0
    STQ(2); STQ(3);

#undef STAGEH
#undef LOADBD
#undef LOADAD
#undef MFMAQ
#undef LGK0
#undef BAR
#undef PRIO1
#undef PRIO0
#undef STQ
}

extern "C" void kernel_launch(void* const* d_in, const int* in_sizes, int n_in,
                              void* d_out, int out_size, void* d_ws, size_t ws_size,
                              hipStream_t stream)
{
    const float* x    = (const float*)d_in[0];
    const float* W    = (const float*)d_in[1];
    const float* bias = (const float*)d_in[2];
    const float* U    = (const float*)d_in[3];
    const float* V    = (const float*)d_in[4];
    const float* A    = (const float*)d_in[5];
    const float* B    = (const float*)d_in[6];
    const float* R    = (const float*)d_in[7];
    const float* C    = (const float*)d_in[8];
    float* out = (float*)d_out;

    char* ws = (char*)d_ws;
    u16*      xB    = (u16*)(ws + XB_OFF);
    u16*      wB    = (u16*)(ws + WB_OFF);
    uint32_t* ctl   = (uint32_t*)(ws + CTL_OFF);
    uint32_t* h1    = (uint32_t*)((char*)ctl + H1_OFF);
    uint32_t* h2    = (uint32_t*)((char*)ctl + H2_OFF);
    uint32_t* cnt3  = (uint32_t*)((char*)ctl + CNT3_OFF);
    uint32_t* list3 = (uint32_t*)((char*)ctl + LIST3_OFF);

    convx_kernel<<<TOKENS*IN_F/8/256, 256, 0, stream>>>(x, xB, ctl);
    prep_kernel<<<OUT_F/2, 256, 0, stream>>>(W, U, V, A, B, R, C, h1);
    hist2r_kernel<<<OUT_F/2, 256, 0, stream>>>(W, U, V, A, B, R, C, h1, h2);
    applyr_kernel<<<OUT_F/2, 256, 0, stream>>>(W, U, V, A, B, R, C, h1, h2, wB, cnt3, list3);
    selfix_kernel<<<1, 256, 0, stream>>>(h1, h2, cnt3, list3, wB);
    gemm256_kernel<<<(TOKENS/256)*(OUT_F/256), 512, 0, stream>>>(xB, wB, bias, out);
}

// Round 18
// 374.986 us; speedup vs baseline: 1.0203x; 1.0203x over previous
//
#include <hip/hip_runtime.h>
#include <stdint.h>

#define TOKENS 8192
#define OUT_F  4096
#define IN_F   4096
#define RNK    8
#define KPRUNE 8388608u
#define CAP3   16384u

typedef unsigned short u16;
typedef float  f32x4  __attribute__((ext_vector_type(4)));
typedef short  bf16x8 __attribute__((ext_vector_type(8)));
typedef unsigned short u16x4 __attribute__((ext_vector_type(4)));
typedef unsigned short u16x8 __attribute__((ext_vector_type(8)));

// ---- workspace layout (bytes) ----
#define XB_OFF    0ull                 // xB  : 8192*4096 bf16 = 64 MiB
#define WB_OFF    67108864ull          // wB  : 4096*4096 bf16 = 32 MiB
#define CTL_OFF   100663296ull
//   ctl: h1[4096] h2[4096] cnt3[1] list3[CAP3]
#define H1_OFF    0
#define H2_OFF    16384
#define CNT3_OFF  32768
#define LIST3_OFF 32772
#define CTL_ZERO_U32 8193              // h1+h2+cnt3

__device__ __forceinline__ u16 f2bf(float f) {
    uint32_t u = __float_as_uint(f);
    u += 0x7fffu + ((u >> 16) & 1u);   // RNE
    return (u16)(u >> 16);
}

__device__ __forceinline__ uint32_t fkey(float s) {
    uint32_t u = __float_as_uint(s);
    return (u & 0x80000000u) ? ~u : (u | 0x80000000u);
}

// ---- inline k-th select over a 4096-bin global histogram (256 threads) ----
__device__ __forceinline__ void hsel(const uint32_t* __restrict__ hist, uint32_t k,
                                     volatile uint32_t* scr,
                                     uint32_t& bin, uint32_t& below)
{
    const int t = threadIdx.x;
    const int lane = t & 63, w = t >> 6;
    uint32_t v[16]; uint32_t s = 0;
#pragma unroll
    for (int j = 0; j < 16; ++j) { v[j] = hist[t*16 + j]; s += v[j]; }
    uint32_t sc = s;                       // inclusive wave scan
#pragma unroll
    for (int d = 1; d < 64; d <<= 1) {
        uint32_t o = __shfl_up(sc, d, 64);
        if (lane >= d) sc += o;
    }
    if (lane == 63) scr[w] = sc;           // wave totals
    __syncthreads();
    uint32_t woff = 0;
    for (int ww = 0; ww < w; ++ww) woff += scr[ww];
    const uint32_t pre = woff + sc - s;    // exclusive prefix of thread t
    if (pre < k && pre + s >= k) {         // unique winner
        uint32_t bb = pre;
#pragma unroll
        for (int j = 0; j < 16; ++j) {
            if (bb < k && bb + v[j] >= k) { scr[4] = (uint32_t)(t*16 + j); scr[5] = bb; }
            bb += v[j];
        }
    }
    __syncthreads();
    bin = scr[4]; below = scr[5];
    __syncthreads();
}

// ---- shared score recompute: 2 rows x 4 cols, IDENTICAL FMA sequence in all
// three passes (dependence-chained fmaf => bit-identical, deterministic).
struct S2 { float4 w0, w1; uint4 k0, k1; };
__device__ __forceinline__ S2 score2(const float* __restrict__ W,
                                     const float* __restrict__ V,
                                     const float* __restrict__ B,
                                     const float* __restrict__ C,
                                     const float* uu0, const float* uu1,
                                     const float* aa0, const float* aa1,
                                     float ro0, float ro1, int o0, int i)
{
    const float4 cc = *(const float4*)&C[i];
    float4 w0 = *(const float4*)&W[(size_t)o0*IN_F + i];
    float4 w1 = *(const float4*)&W[(size_t)(o0+1)*IN_F + i];
#pragma unroll
    for (int r = 0; r < RNK; ++r) {
        const float4 v4 = *(const float4*)&V[r*IN_F + i];
        const float a0 = uu0[r], a1 = uu1[r];
        w0.x = fmaf(a0, v4.x, w0.x); w0.y = fmaf(a0, v4.y, w0.y);
        w0.z = fmaf(a0, v4.z, w0.z); w0.w = fmaf(a0, v4.w, w0.w);
        w1.x = fmaf(a1, v4.x, w1.x); w1.y = fmaf(a1, v4.y, w1.y);
        w1.z = fmaf(a1, v4.z, w1.z); w1.w = fmaf(a1, v4.w, w1.w);
    }
    float4 s0, s1;
    s0.x = fabsf(w0.x); s0.y = fabsf(w0.y); s0.z = fabsf(w0.z); s0.w = fabsf(w0.w);
    s1.x = fabsf(w1.x); s1.y = fabsf(w1.y); s1.z = fabsf(w1.z); s1.w = fabsf(w1.w);
#pragma unroll
    for (int r = 0; r < RNK; ++r) {
        const float4 b4 = *(const float4*)&B[r*IN_F + i];
        const float a0 = aa0[r], a1 = aa1[r];
        s0.x = fmaf(a0, b4.x, s0.x); s0.y = fmaf(a0, b4.y, s0.y);
        s0.z = fmaf(a0, b4.z, s0.z); s0.w = fmaf(a0, b4.w, s0.w);
        s1.x = fmaf(a1, b4.x, s1.x); s1.y = fmaf(a1, b4.y, s1.y);
        s1.z = fmaf(a1, b4.z, s1.z); s1.w = fmaf(a1, b4.w, s1.w);
    }
    s0.x += ro0 + cc.x; s0.y += ro0 + cc.y; s0.z += ro0 + cc.z; s0.w += ro0 + cc.w;
    s1.x += ro1 + cc.x; s1.y += ro1 + cc.y; s1.z += ro1 + cc.z; s1.w += ro1 + cc.w;
    S2 o;
    o.w0 = w0; o.w1 = w1;
    o.k0.x = fkey(s0.x); o.k0.y = fkey(s0.y); o.k0.z = fkey(s0.z); o.k0.w = fkey(s0.w);
    o.k1.x = fkey(s1.x); o.k1.y = fkey(s1.y); o.k1.z = fkey(s1.z); o.k1.w = fkey(s1.w);
    return o;
}

#define LOAD_ROWPARAMS                                                        \
    float uu0[RNK], uu1[RNK], aa0[RNK], aa1[RNK];                             \
    _Pragma("unroll") for (int r = 0; r < RNK; ++r) {                         \
        uu0[r] = U[o0*RNK + r];   uu1[r] = U[(o0+1)*RNK + r];                 \
        aa0[r] = A[o0*RNK + r];   aa1[r] = A[(o0+1)*RNK + r];                 \
    }                                                                         \
    const float ro0 = R[o0], ro1 = R[o0 + 1];

// ---------------- x -> bf16 (+ ctl zeroing folded in) ----------------
__global__ void convx_kernel(const float* __restrict__ x, u16* __restrict__ xB,
                             uint32_t* __restrict__ ctl)
{
    const int t = threadIdx.x;
    if (blockIdx.x < 33) {
        const int i = blockIdx.x * 256 + t;
        if (i < CTL_ZERO_U32) ctl[i] = 0u;
    }
    const size_t idx = (size_t)blockIdx.x * 256 + t;
    const float4* xv = (const float4*)x;
    float4 a = xv[idx*2];
    float4 b = xv[idx*2 + 1];
    u16x8 o;
    o[0]=f2bf(a.x); o[1]=f2bf(a.y); o[2]=f2bf(a.z); o[3]=f2bf(a.w);
    o[4]=f2bf(b.x); o[5]=f2bf(b.y); o[6]=f2bf(b.z); o[7]=f2bf(b.w);
    *((u16x8*)xB + idx) = o;
}

// ---------------- pass 1: 12-bit histogram only (no stores) ----------------
__global__ void prep_kernel(const float* __restrict__ W, const float* __restrict__ U,
                            const float* __restrict__ V, const float* __restrict__ A,
                            const float* __restrict__ B, const float* __restrict__ R,
                            const float* __restrict__ C, uint32_t* __restrict__ hist1)
{
    __shared__ uint32_t lh[4096];
    const int o0 = blockIdx.x * 2, t = threadIdx.x;
    for (int b = t; b < 4096; b += 256) lh[b] = 0u;
    LOAD_ROWPARAMS
    __syncthreads();
    for (int j = 0; j < IN_F/1024; ++j) {
        const int i = j*1024 + t*4;
        S2 s = score2(W, V, B, C, uu0, uu1, aa0, aa1, ro0, ro1, o0, i);
        atomicAdd(&lh[s.k0.x >> 20], 1u); atomicAdd(&lh[s.k0.y >> 20], 1u);
        atomicAdd(&lh[s.k0.z >> 20], 1u); atomicAdd(&lh[s.k0.w >> 20], 1u);
        atomicAdd(&lh[s.k1.x >> 20], 1u); atomicAdd(&lh[s.k1.y >> 20], 1u);
        atomicAdd(&lh[s.k1.z >> 20], 1u); atomicAdd(&lh[s.k1.w >> 20], 1u);
    }
    __syncthreads();
    for (int b = t; b < 4096; b += 256) { uint32_t c = lh[b]; if (c) atomicAdd(&hist1[b], c); }
}

// ---------------- pass 2: inline select1 + mid-12 histogram within b1 ----------------
__global__ void hist2r_kernel(const float* __restrict__ W, const float* __restrict__ U,
                              const float* __restrict__ V, const float* __restrict__ A,
                              const float* __restrict__ B, const float* __restrict__ R,
                              const float* __restrict__ C, const uint32_t* __restrict__ hist1,
                              uint32_t* __restrict__ hist2)
{
    __shared__ uint32_t lh[4096];
    __shared__ uint32_t scr[6];
    const int o0 = blockIdx.x * 2, t = threadIdx.x;
    uint32_t b1, below1;
    hsel(hist1, KPRUNE, scr, b1, below1);
    for (int b = t; b < 4096; b += 256) lh[b] = 0u;
    LOAD_ROWPARAMS
    __syncthreads();
    for (int j = 0; j < IN_F/1024; ++j) {
        const int i = j*1024 + t*4;
        S2 s = score2(W, V, B, C, uu0, uu1, aa0, aa1, ro0, ro1, o0, i);
        if ((s.k0.x >> 20) == b1) atomicAdd(&lh[(s.k0.x >> 8) & 0xFFFu], 1u);
        if ((s.k0.y >> 20) == b1) atomicAdd(&lh[(s.k0.y >> 8) & 0xFFFu], 1u);
        if ((s.k0.z >> 20) == b1) atomicAdd(&lh[(s.k0.z >> 8) & 0xFFFu], 1u);
        if ((s.k0.w >> 20) == b1) atomicAdd(&lh[(s.k0.w >> 8) & 0xFFFu], 1u);
        if ((s.k1.x >> 20) == b1) atomicAdd(&lh[(s.k1.x >> 8) & 0xFFFu], 1u);
        if ((s.k1.y >> 20) == b1) atomicAdd(&lh[(s.k1.y >> 8) & 0xFFFu], 1u);
        if ((s.k1.z >> 20) == b1) atomicAdd(&lh[(s.k1.z >> 8) & 0xFFFu], 1u);
        if ((s.k1.w >> 20) == b1) atomicAdd(&lh[(s.k1.w >> 8) & 0xFFFu], 1u);
    }
    __syncthreads();
    for (int b = t; b < 4096; b += 256) { uint32_t c = lh[b]; if (c) atomicAdd(&hist2[b], c); }
}

// ---------------- pass 3: inline selects, write FINAL masked wB, collect ties ----------------
__global__ void applyr_kernel(const float* __restrict__ W, const float* __restrict__ U,
                              const float* __restrict__ V, const float* __restrict__ A,
                              const float* __restrict__ B, const float* __restrict__ R,
                              const float* __restrict__ C, const uint32_t* __restrict__ hist1,
                              const uint32_t* __restrict__ hist2, u16* __restrict__ wB,
                              uint32_t* __restrict__ cnt3, uint32_t* __restrict__ list3)
{
    __shared__ uint32_t scr[6];
    const int o0 = blockIdx.x * 2, t = threadIdx.x;
    uint32_t b1, below1, b2, below2;
    hsel(hist1, KPRUNE, scr, b1, below1);
    hsel(hist2, KPRUNE - below1, scr, b2, below2);
    const uint32_t pfx = (b1 << 12) | b2;
    LOAD_ROWPARAMS
    for (int j = 0; j < IN_F/1024; ++j) {
        const int i = j*1024 + t*4;
        S2 s = score2(W, V, B, C, uu0, uu1, aa0, aa1, ro0, ro1, o0, i);
        const float w0a[4] = {s.w0.x, s.w0.y, s.w0.z, s.w0.w};
        const float w1a[4] = {s.w1.x, s.w1.y, s.w1.z, s.w1.w};
        const uint32_t k0a[4] = {s.k0.x, s.k0.y, s.k0.z, s.k0.w};
        const uint32_t k1a[4] = {s.k1.x, s.k1.y, s.k1.z, s.k1.w};
        u16x4 b0, b1v;
#pragma unroll
        for (int e = 0; e < 4; ++e) {
            const uint32_t hi = k0a[e] >> 8;
            b0[e] = (hi < pfx) ? (u16)0 : f2bf(w0a[e]);
            if (hi == pfx) {
                uint32_t sl = atomicAdd(cnt3, 1u);
                if (sl < CAP3) list3[sl] = ((uint32_t)(o0*IN_F + i + e) << 8) | (k0a[e] & 0xFFu);
            }
        }
#pragma unroll
        for (int e = 0; e < 4; ++e) {
            const uint32_t hi = k1a[e] >> 8;
            b1v[e] = (hi < pfx) ? (u16)0 : f2bf(w1a[e]);
            if (hi == pfx) {
                uint32_t sl = atomicAdd(cnt3, 1u);
                if (sl < CAP3) list3[sl] = ((uint32_t)((o0+1)*IN_F + i + e) << 8) | (k1a[e] & 0xFFu);
            }
        }
        *(u16x4*)&wB[(size_t)o0*IN_F + i]     = b0;
        *(u16x4*)&wB[(size_t)(o0+1)*IN_F + i] = b1v;
    }
}

// ---------------- selfix: inline selects + exact stable pruning within prefix ----------------
__global__ void selfix_kernel(const uint32_t* __restrict__ hist1, const uint32_t* __restrict__ hist2,
                              const uint32_t* __restrict__ cnt3, const uint32_t* __restrict__ list3,
                              u16* __restrict__ wB)
{
    __shared__ uint32_t lst[CAP3];
    __shared__ uint32_t lhist[256];
    __shared__ uint32_t sv[2];
    __shared__ uint32_t scr[6];
    const int t = threadIdx.x;
    uint32_t b1, below1, b2, below2;
    hsel(hist1, KPRUNE, scr, b1, below1);
    hsel(hist2, KPRUNE - below1, scr, b2, below2);
    const uint32_t k3 = KPRUNE - below1 - below2;   // >= 1
    uint32_t n = *cnt3; if (n > CAP3) n = CAP3;
    lhist[t] = 0u;
    __syncthreads();
    for (uint32_t i = t; i < n; i += 256) {
        const uint32_t e = list3[i];
        lst[i] = e;
        atomicAdd(&lhist[e & 0xFFu], 1u);
    }
    __syncthreads();
    uint32_t pre = 0;
    for (int b = 0; b < t; ++b) pre += lhist[b];
    if (pre < k3 && pre + lhist[t] >= k3) {
        sv[0] = (uint32_t)t;
        sv[1] = k3 - pre;                    // ties at b3 to prune (>=1)
    }
    __syncthreads();
    const uint32_t b3 = sv[0], p = sv[1];
    for (uint32_t i = t; i < n; i += 256) {
        const uint32_t e = lst[i];
        const uint32_t lo = e & 0xFFu;
        if (lo < b3) { wB[e >> 8] = 0u; continue; }
        if (lo != b3) continue;
        uint32_t rank = 0;
        for (uint32_t j = 0; j < n; ++j) {
            const uint32_t f = lst[j];
            rank += ((f & 0xFFu) == b3 && f < e) ? 1u : 0u;   // same low8 -> flat-idx order
        }
        if (rank < p) wB[e >> 8] = 0u;
    }
}

// == 256x256 8-phase bf16 NT GEMM + B/A register prefetch + thinned barriers ==
// (R16 configuration — best measured. R17's phase-merge regressed: the fine
// phase granularity enforces wave interleave so MFMA and staging overlap.)
#define A0H0   0
#define A0H1_0 16384
#define A0H1_1 32768
#define B0S    49152
#define A1H0   81920
#define A1H1_0 98304
#define A1H1_1 114688
#define B1S    131072

__device__ __forceinline__ void gl_lds16(const char* src, char* dst) {
    __builtin_amdgcn_global_load_lds((const __attribute__((address_space(1))) void*)src,
                                     (__attribute__((address_space(3))) void*)dst, 16, 0, 0);
}

__global__ __launch_bounds__(512, 2) void gemm256_kernel(const u16* __restrict__ xB,
                                                         const u16* __restrict__ wB,
                                                         const float* __restrict__ bias,
                                                         float* __restrict__ out)
{
    __shared__ char ldsc[163840];
    const int t    = threadIdx.x;
    const int lane = t & 63;
    const int wid  = t >> 6;
    const int wm   = wid >> 2;     // 0..1
    const int wn   = wid & 3;      // 0..3
    const int bid  = blockIdx.x;
    const int bn   = bid & 15;     // N/256 = 16
    const int bm   = bid >> 4;     // M/256 = 32

    const int l15 = lane & 15;
    const int kb  = (lane >> 4) << 4;
    const int rowA = 16*wm + l15;
    const int rowB = (wn & 1)*64 + l15;
    const int baseA = rowA*64 + (kb ^ (((rowA >> 1) & 3) << 4));
    const int baseB = rowB*64 + (kb ^ (((rowB >> 1) & 3) << 4));
    const char* aB0 = ldsc + baseA;
    const char* aB1 = ldsc + A1H0 + baseA;
    const char* bB0 = ldsc + B0S + (wn >> 1)*16384 + baseB;
    const char* bB1 = bB0 + (B1S - B0S);

    const int scol = ((t & 3) * 16) ^ (((t >> 3) & 3) << 4);
    const char* pA = (const char*)xB + ((size_t)(bm*256 + (t >> 2))) * (IN_F*2) + scol;
    const char* pB = (const char*)wB + ((size_t)(bn*256 + (t >> 2))) * (IN_F*2) + scol;
    const int tb16 = t * 16;

#define STAGEH(pG, slot, h, tile) do {                                        \
    const char* _s = (pG) + (size_t)(tile)*128 + (size_t)(h)*(128*IN_F*2);    \
    char* _d = ldsc + (slot) + tb16;                                          \
    gl_lds16(_s, _d);                                                         \
    gl_lds16(_s + 64, _d + 8192);                                             \
} while (0)

    f32x4  acc[8][4] = {};
    bf16x8 be[4][2], bo[4][2];     // B register double-buffer (even/odd tiles)
    bf16x8 au[2][2], av[2][2];     // A quadrant double-buffer

#define LOADBD(dst, bp) do {                                                  \
    _Pragma("unroll") for (int ni = 0; ni < 4; ++ni)                          \
    _Pragma("unroll") for (int kk = 0; kk < 2; ++kk)                          \
        dst[ni][kk] = *(const bf16x8*)((bp) + ni*1024 + kk*8192);             \
} while (0)

#define LOADAD(dst, ap, slot, q, mo) do {                                     \
    _Pragma("unroll") for (int mm = 0; mm < 2; ++mm)                          \
    _Pragma("unroll") for (int kk = 0; kk < 2; ++kk)                          \
        dst[mm][kk] = *(const bf16x8*)((ap) + (slot) +                        \
                      (2*(q)+mm-(mo))*2048 + kk*8192);                        \
} while (0)

#define MFMAQ(q, bb, aa) do {                                                 \
    _Pragma("unroll") for (int mm = 0; mm < 2; ++mm)                          \
    _Pragma("unroll") for (int ni = 0; ni < 4; ++ni)                          \
    _Pragma("unroll") for (int kk = 0; kk < 2; ++kk)                          \
        acc[2*(q)+mm][ni] = __builtin_amdgcn_mfma_f32_16x16x32_bf16(          \
            aa[mm][kk], bb[ni][kk], acc[2*(q)+mm][ni], 0, 0, 0);              \
} while (0)

// phase tail WITHOUT leading barrier (preload sources proven by earlier barrier)
#define PH_NB(q, bb, aa, PRELOAD)                                             \
    asm volatile("s_waitcnt lgkmcnt(0)" ::: "memory");                        \
    __builtin_amdgcn_s_setprio(1);                                            \
    MFMAQ(q, bb, aa);                                                         \
    PRELOAD;                                                                  \
    __builtin_amdgcn_s_setprio(0);                                            \
    __builtin_amdgcn_s_barrier();

// phase tail WITH leading barrier (ph4/ph8: upgrades vmcnt to cross-wave)
#define PH_B(q, bb, aa, PRELOAD)                                              \
    __builtin_amdgcn_s_barrier();                                             \
    asm volatile("s_waitcnt lgkmcnt(0)" ::: "memory");                        \
    __builtin_amdgcn_s_setprio(1);                                            \
    MFMAQ(q, bb, aa);                                                         \
    PRELOAD;                                                                  \
    __builtin_amdgcn_s_setprio(0);                                            \
    __builtin_amdgcn_s_barrier();

#define STQ(q) do {                                                           \
    _Pragma("unroll") for (int mm = 0; mm < 2; ++mm) {                        \
        const int r0 = orow0 + 32*(2*(q)+mm);                                 \
        _Pragma("unroll") for (int ni = 0; ni < 4; ++ni) {                    \
            f32x4 v = acc[2*(q)+mm][ni];                                      \
            const int col = ocol0 + ni*16;                                    \
            _Pragma("unroll") for (int e = 0; e < 4; ++e)                     \
                out[(size_t)(r0 + e)*OUT_F + col] = v[e] + bv[ni];            \
        }                                                                     \
    }                                                                         \
} while (0)

#define PH_NB_ST(q, bb, aa, PRELOAD)                                          \
    asm volatile("s_waitcnt lgkmcnt(0)" ::: "memory");                        \
    __builtin_amdgcn_s_setprio(1);                                            \
    MFMAQ(q, bb, aa);                                                         \
    PRELOAD;                                                                  \
    __builtin_amdgcn_s_setprio(0);                                            \
    STQ(q);

    // ---- prologue
    STAGEH(pA, A0H1_0, 1, 0);
    STAGEH(pB, B0S,         0, 0);
    STAGEH(pB, B0S + 16384, 1, 0);
    STAGEH(pA, A0H0, 0, 0);
    STAGEH(pA, A1H1_0, 1, 1);
    STAGEH(pB, B1S,         0, 1);
    STAGEH(pB, B1S + 16384, 1, 1);
    STAGEH(pA, A1H0, 0, 1);
    asm volatile("s_waitcnt vmcnt(8)" ::: "memory");   // tile0's 4 half-tiles landed
    __builtin_amdgcn_s_barrier();
    LOADBD(be, bB0);                                   // tile0 B -> regs
    LOADAD(au, aB0, A0H0, 0, 0);                       // tile0 A-q0 -> regs

#pragma unroll 1
    for (int j = 0; j < 31; ++j) {          // tiles 0..61; 62,63 peeled
        const int se = 2*j + 2;
        const int so = 2*j + 3;
        const int pc = j & 1;
        const int a0h1c = pc ? A0H1_1 : A0H1_0;
        const int a0h1n = pc ? A0H1_0 : A0H1_1;
        const int a1h1c = pc ? A1H1_1 : A1H1_0;
        const int a1h1n = pc ? A1H1_0 : A1H1_1;

        // ---- even tile 2j (B=be) ----
        STAGEH(pA, a0h1n, 1, se);
        PH_NB(0, be, au, LOADAD(av, aB0, A0H0, 1, 0))
        STAGEH(pB, B0S, 0, se);
        PH_NB(1, be, av, LOADAD(au, aB0, a0h1c, 2, 4))
        STAGEH(pB, B0S + 16384, 1, se);
        PH_NB(2, be, au, LOADAD(av, aB0, a0h1c, 3, 4))
        STAGEH(pA, A0H0, 0, se);
        asm volatile("s_waitcnt vmcnt(8)" ::: "memory");   // odd tile 2j+1 landed
        PH_B(3, be, av, { LOADBD(bo, bB1); LOADAD(au, aB1, 0, 0, 0); })

        // ---- odd tile 2j+1 (B=bo) ----
        STAGEH(pA, a1h1n, 1, so);
        PH_NB(0, bo, au, LOADAD(av, aB1, 0, 1, 0))
        STAGEH(pB, B1S, 0, so);
        PH_NB(1, bo, av, LOADAD(au, aB1, a1h1c - A1H0, 2, 4))
        STAGEH(pB, B1S + 16384, 1, so);
        PH_NB(2, bo, au, LOADAD(av, aB1, a1h1c - A1H0, 3, 4))
        STAGEH(pA, A1H0, 0, so);
        asm volatile("s_waitcnt vmcnt(8)" ::: "memory");   // even tile 2j+2 landed
        PH_B(3, bo, av, { LOADBD(be, bB0); LOADAD(au, aB0, A0H0, 0, 0); })
    }

    // ---- peeled tiles 62 + 63: no staging; stores fused into tile 63
    const int orow0 = bm*256 + 16*wm + ((lane >> 4) << 2);
    const int ocol0 = bn*256 + 64*wn + l15;
    float bv[4];
#pragma unroll
    for (int ni = 0; ni < 4; ++ni) bv[ni] = bias[ocol0 + ni*16];

    // tile 62 (even; be + au-q0 prefetched at j=30 ph8); parity j=31 -> *_1 slots
    PH_NB(0, be, au, LOADAD(av, aB0, A0H0, 1, 0))
    PH_NB(1, be, av, LOADAD(au, aB0, A0H1_1, 2, 4))
    PH_NB(2, be, au, LOADAD(av, aB0, A0H1_1, 3, 4))
    asm volatile("s_waitcnt vmcnt(0)" ::: "memory");       // tile 63 landed
    PH_B(3, be, av, { LOADBD(bo, bB1); LOADAD(au, aB1, 0, 0, 0); })

    // tile 63 (odd; B=bo), stores fused per quadrant (no LDS writes -> no barriers)
    PH_NB_ST(0, bo, au, LOADAD(av, aB1, 0, 1, 0))
    PH_NB_ST(1, bo, av, LOADAD(au, aB1, A1H1_1 - A1H0, 2, 4))
    PH_NB_ST(2, bo, au, LOADAD(av, aB1, A1H1_1 - A1H0, 3, 4))
    PH_NB_ST(3, bo, av, (void)0)

#undef STAGEH
#undef LOADBD
#undef LOADAD
#undef MFMAQ
#undef PH_NB
#undef PH_B
#undef PH_NB_ST
#undef STQ
}

extern "C" void kernel_launch(void* const* d_in, const int* in_sizes, int n_in,
                              void* d_out, int out_size, void* d_ws, size_t ws_size,
                              hipStream_t stream)
{
    const float* x    = (const float*)d_in[0];
    const float* W    = (const float*)d_in[1];
    const float* bias = (const float*)d_in[2];
    const float* U    = (const float*)d_in[3];
    const float* V    = (const float*)d_in[4];
    const float* A    = (const float*)d_in[5];
    const float* B    = (const float*)d_in[6];
    const float* R    = (const float*)d_in[7];
    const float* C    = (const float*)d_in[8];
    float* out = (float*)d_out;

    char* ws = (char*)d_ws;
    u16*      xB    = (u16*)(ws + XB_OFF);
    u16*      wB    = (u16*)(ws + WB_OFF);
    uint32_t* ctl   = (uint32_t*)(ws + CTL_OFF);
    uint32_t* h1    = (uint32_t*)((char*)ctl + H1_OFF);
    uint32_t* h2    = (uint32_t*)((char*)ctl + H2_OFF);
    uint32_t* cnt3  = (uint32_t*)((char*)ctl + CNT3_OFF);
    uint32_t* list3 = (uint32_t*)((char*)ctl + LIST3_OFF);

    convx_kernel<<<TOKENS*IN_F/8/256, 256, 0, stream>>>(x, xB, ctl);
    prep_kernel<<<OUT_F/2, 256, 0, stream>>>(W, U, V, A, B, R, C, h1);
    hist2r_kernel<<<OUT_F/2, 256, 0, stream>>>(W, U, V, A, B, R, C, h1, h2);
    applyr_kernel<<<OUT_F/2, 256, 0, stream>>>(W, U, V, A, B, R, C, h1, h2, wB, cnt3, list3);
    selfix_kernel<<<1, 256, 0, stream>>>(h1, h2, cnt3, list3, wB);
    gemm256_kernel<<<(TOKENS/256)*(OUT_F/256), 512, 0, stream>>>(xB, wB, bias, out);
}